// Round 1
// baseline (4622.395 us; speedup 1.0000x reference)
//
#include <hip/hip_runtime.h>
#include <cmath>

// Problem constants
// IDIM=256, CDIM=512, NH=2, N=128, M=64, T=64, BSZ=128
// K = IDIM + NH*M (=384) + CDIM (=512) = 896 ; gate rows = 4*CDIM = 2048

// ---- ws float offsets ----
// mem    [128][128][64]           @ 0          (1,048,576)
// h      [128][512]               @ 1,048,576  (65,536)
// c      [128][512]               @ 1,114,112  (65,536)
// reads  [2][128][64]             @ 1,179,648  (16,384)
// rw     [2][128][128]            @ 1,196,032  (32,768)
// wws    [2][128][128]            @ 1,228,800  (32,768)
// scratch (partials [4][128][2048] OR part2 [4][544][128]) @ 1,261,568 (1,048,576)
// total floats = 2,310,144  (~9.24 MB)

__device__ __forceinline__ float sigm(float x) { return 1.0f / (1.0f + expf(-x)); }
__device__ __forceinline__ float softplusf(float x) {
    return fmaxf(x, 0.0f) + log1pf(expf(-fabsf(x)));
}

// ---------------- init: broadcast initial state into ws ----------------
__global__ void k_init(float* __restrict__ ws,
                       const float* __restrict__ mem_bias,
                       const float* __restrict__ h0,
                       const float* __restrict__ c0,
                       const float* __restrict__ r0)
{
    int i = blockIdx.x * 256 + threadIdx.x;          // 0 .. 1,261,567
    if (i < 1048576) { ws[i] = mem_bias[i & 8191]; return; }       // mem
    int j = i - 1048576;
    if (j < 65536)   { ws[i] = h0[j & 511]; return; }              // h
    j -= 65536;
    if (j < 65536)   { ws[i] = c0[j & 511]; return; }              // c
    j -= 65536;
    if (j < 16384)   { ws[i] = r0[((j >> 13) << 6) | (j & 63)]; return; } // reads
    j -= 16384;
    if (j < 65536)   { ws[i] = 0.0f; return; }                     // rw + wws
}

// ---------------- k1a: gates GEMM (K-split partials) ----------------
// grid (16 row-tiles of 128, 4 b-tiles of 32, 4 K-splits of 224), 256 thr
// thread tile 4r x 4b. partials layout [ks][b][2048 rows]
__global__ __launch_bounds__(256) void k_gates_gemm(
    const float* __restrict__ embs,   // (64,128,256)
    const float* __restrict__ W_ih,   // (2048,384)
    const float* __restrict__ W_hh,   // (2048,512)
    const float* __restrict__ ws,
    float* __restrict__ partials,
    int t)
{
    const int tx = threadIdx.x;
    const int r0 = blockIdx.x * 128;
    const int b0 = blockIdx.y * 32;
    const int kz = blockIdx.z;        // K chunk of 224
    const int rg = tx >> 3;           // 0..31
    const int bg = tx & 7;            // 0..7

    __shared__ float w_s[128][33];    // stride 33 -> banks (r+kk)%32, conflict-free
    __shared__ float x_s[32][33];

    float acc[4][4];
#pragma unroll
    for (int i = 0; i < 4; ++i)
#pragma unroll
        for (int j = 0; j < 4; ++j) acc[i][j] = 0.f;

    const float* hptr = ws + 1048576;
    const float* rptr = ws + 1179648;

    for (int kc = 0; kc < 7; ++kc) {
        const int kb = kz * 224 + kc * 32;
        // stage W: 128 rows x 32 k  (coalesced: tx -> consecutive k)
#pragma unroll
        for (int e = 0; e < 16; ++e) {
            int flat = e * 256 + tx;
            int rl = flat >> 5, kk = flat & 31;
            int r = r0 + rl, kg = kb + kk;
            float v = (kg < 384) ? W_ih[r * 384 + kg] : W_hh[r * 512 + (kg - 384)];
            w_s[rl][kk] = v;
        }
        // stage x/h: 32 b x 32 k  (chunk boundaries at multiples of 32 -> uniform source)
#pragma unroll
        for (int e = 0; e < 4; ++e) {
            int flat = e * 256 + tx;
            int bl = flat >> 5, kk = flat & 31;
            int b = b0 + bl, kg = kb + kk;
            float v;
            if      (kg < 256) v = embs[(t * 128 + b) * 256 + kg];
            else if (kg < 320) v = rptr[b * 64 + (kg - 256)];
            else if (kg < 384) v = rptr[8192 + b * 64 + (kg - 320)];
            else               v = hptr[b * 512 + (kg - 384)];
            x_s[bl][kk] = v;
        }
        __syncthreads();
#pragma unroll
        for (int kk = 0; kk < 32; ++kk) {
            float wv[4], xv[4];
#pragma unroll
            for (int i = 0; i < 4; ++i) wv[i] = w_s[rg * 4 + i][kk];
#pragma unroll
            for (int j = 0; j < 4; ++j) xv[j] = x_s[bg * 4 + j][kk];
#pragma unroll
            for (int i = 0; i < 4; ++i)
#pragma unroll
                for (int j = 0; j < 4; ++j) acc[i][j] += wv[i] * xv[j];
        }
        __syncthreads();
    }
#pragma unroll
    for (int j = 0; j < 4; ++j) {
        int b = b0 + bg * 4 + j;
        float4 v = make_float4(acc[0][j], acc[1][j], acc[2][j], acc[3][j]);
        *reinterpret_cast<float4*>(&partials[(size_t)kz * 262144 + b * 2048 + r0 + rg * 4]) = v;
    }
}

// ---------------- k1b: LSTM pointwise ----------------
__global__ __launch_bounds__(256) void k_lstm(
    const float* __restrict__ partials,
    const float* __restrict__ b_ih,
    const float* __restrict__ b_hh,
    float* __restrict__ ws,
    float* __restrict__ d_out,
    const int* __restrict__ lens,
    int t)
{
    int cell = blockIdx.x * 256 + threadIdx.x;   // 65536 = 128b x 512ch
    int b = cell >> 9, ch = cell & 511;
    float gate[4];
#pragma unroll
    for (int g = 0; g < 4; ++g) {
        int r = g * 512 + ch;
        float s = b_ih[r] + b_hh[r];
#pragma unroll
        for (int ks = 0; ks < 4; ++ks) s += partials[(size_t)ks * 262144 + b * 2048 + r];
        gate[g] = s;
    }
    float* hp = ws + 1048576;
    float* cp = ws + 1114112;
    float c_old = cp[cell];
    float c_new = sigm(gate[1]) * c_old + sigm(gate[0]) * tanhf(gate[2]);
    float h_new = sigm(gate[3]) * tanhf(c_new);
    cp[cell] = c_new;
    hp[cell] = h_new;
    d_out[((size_t)t * 128 + b) * 640 + ch] = h_new;
    if (lens[b] - 1 == t) {
        d_out[5242880 + cell] = h_new;   // h_fin
        d_out[5308416 + cell] = c_new;   // c_fin
    }
}

// ---------------- k2: head projections (K-split partials) ----------------
// rows j in [0,536): head hi = j>=268; q=j-268*hi; q<70 -> Wr[hi], else Ww[hi] row q-70
// grid (17 j-tiles of 32, 2 b-tiles of 64, 4 K-splits of 128), 256 thr, thread 2j x 4b
// part2 layout [ks][544][128]
__global__ __launch_bounds__(256) void k_proj(
    const float* __restrict__ ws,
    const float* __restrict__ Wr,     // (2,70,512)
    const float* __restrict__ Ww,     // (2,198,512)
    float* __restrict__ part2)
{
    const int tx = threadIdx.x;
    const int j0 = blockIdx.x * 32;
    const int b0 = blockIdx.y * 64;
    const int kz = blockIdx.z;
    const int jg = tx >> 4;           // 0..15
    const int bg = tx & 15;           // 0..15

    __shared__ float w_s[32][33];
    __shared__ float h_s[64][33];

    const float* hptr = ws + 1048576;
    float acc[2][4] = {{0, 0, 0, 0}, {0, 0, 0, 0}};

    for (int kc = 0; kc < 4; ++kc) {
        int kb = kz * 128 + kc * 32;
#pragma unroll
        for (int e = 0; e < 4; ++e) {
            int flat = e * 256 + tx;
            int rl = flat >> 5, kk = flat & 31;
            int j = j0 + rl;
            float v = 0.f;
            if (j < 536) {
                int hi = j >= 268;
                int q = j - hi * 268;
                v = (q < 70) ? Wr[(hi * 70 + q) * 512 + kb + kk]
                             : Ww[(hi * 198 + (q - 70)) * 512 + kb + kk];
            }
            w_s[rl][kk] = v;
        }
#pragma unroll
        for (int e = 0; e < 8; ++e) {
            int flat = e * 256 + tx;
            int bl = flat >> 5, kk = flat & 31;
            h_s[bl][kk] = hptr[(b0 + bl) * 512 + kb + kk];
        }
        __syncthreads();
#pragma unroll
        for (int kk = 0; kk < 32; ++kk) {
            float wv[2], hv[4];
            wv[0] = w_s[jg * 2][kk];
            wv[1] = w_s[jg * 2 + 1][kk];
#pragma unroll
            for (int q = 0; q < 4; ++q) hv[q] = h_s[bg * 4 + q][kk];
#pragma unroll
            for (int i = 0; i < 2; ++i)
#pragma unroll
                for (int q = 0; q < 4; ++q) acc[i][q] += wv[i] * hv[q];
        }
        __syncthreads();
    }
#pragma unroll
    for (int i = 0; i < 2; ++i) {
        int j = j0 + jg * 2 + i;
        float4 v = make_float4(acc[i][0], acc[i][1], acc[i][2], acc[i][3]);
        *reinterpret_cast<float4*>(&part2[(size_t)kz * 69632 + j * 128 + b0 + bg * 4]) = v;
    }
}

// ---------------- k3: per-batch memory ops ----------------
__device__ __forceinline__ float red128(float v, float* red_s, int tx, bool is_max)
{
    if (tx < 128) red_s[tx] = v;
    __syncthreads();
    for (int s = 64; s > 0; s >>= 1) {
        if (tx < s) {
            float a = red_s[tx], bv = red_s[tx + s];
            red_s[tx] = is_max ? fmaxf(a, bv) : (a + bv);
        }
        __syncthreads();
    }
    float r = red_s[0];
    __syncthreads();
    return r;
}

// one NTM addressing pass: p = 70 params {k[64], beta, g, s[3], gamma}
__device__ void ntm_address(const float* __restrict__ p,
                            const float* __restrict__ mem_s,   // [128][65]
                            float* __restrict__ wprev,         // global, 128
                            float* __restrict__ w_out,         // LDS 128
                            float* __restrict__ wg_s,          // LDS 128
                            float* __restrict__ red_s,         // LDS 128
                            int tx)
{
    float beta = softplusf(p[64]);
    float g = sigm(p[65]);
    float s0 = p[66], s1 = p[67], s2 = p[68];
    float sm = fmaxf(s0, fmaxf(s1, s2));
    float e0 = expf(s0 - sm), e1 = expf(s1 - sm), e2 = expf(s2 - sm);
    float sden = e0 + e1 + e2;
    s0 = e0 / sden; s1 = e1 / sden; s2 = e2 / sden;
    float gamma = 1.0f + softplusf(p[69]);
    float nk = 0.f;
    for (int m = 0; m < 64; ++m) { float kv = p[m] + 1e-16f; nk += kv * kv; }
    nk = sqrtf(nk);

    float z;
    if (tx < 128) {
        float dot = 0.f, nm = 0.f;
        for (int m = 0; m < 64; ++m) {
            float mv = mem_s[tx * 65 + m] + 1e-16f;
            float kv = p[m] + 1e-16f;
            dot += mv * kv;
            nm += mv * mv;
        }
        float sim = dot / fmaxf(sqrtf(nm) * nk, 1e-8f);
        z = beta * sim;
    } else z = -1e30f;

    float zmax = red128(z, red_s, tx, true);
    float ez = (tx < 128) ? expf(z - zmax) : 0.f;
    float zsum = red128(ez, red_s, tx, false);
    if (tx < 128) {
        float wc = ez / zsum;
        wg_s[tx] = g * wc + (1.f - g) * wprev[tx];
    }
    __syncthreads();
    float wp = 0.f;
    if (tx < 128) {
        float wwv = s0 * wg_s[(tx + 127) & 127] + s1 * wg_s[tx] + s2 * wg_s[(tx + 1) & 127];
        wp = powf(wwv, gamma);
    }
    float psum = red128(wp, red_s, tx, false);
    if (tx < 128) {
        float wv = wp / (psum + 1e-16f);
        w_out[tx] = wv;
        wprev[tx] = wv;
    }
    __syncthreads();
}

__global__ __launch_bounds__(256) void k_memops(
    const float* __restrict__ part2,
    const float* __restrict__ br,     // (2,70)
    const float* __restrict__ bw,     // (2,198)
    float* __restrict__ ws,
    float* __restrict__ d_out,
    int t)
{
    const int b = blockIdx.x;
    const int tx = threadIdx.x;
    __shared__ float mem_s[128 * 65];
    __shared__ float proj_s[544];
    __shared__ float w_s[128];
    __shared__ float wg_s[128];
    __shared__ float red_s[128];
    __shared__ float ea_s[128];

    float* memg   = ws;
    float* readsg = ws + 1179648;
    float* rwg    = ws + 1196032;
    float* wwsg   = ws + 1228800;

    // proj[b][j] = bias[j] + sum_ks part2[ks][j][b]
    for (int j = tx; j < 544; j += 256) {
        float s = 0.f;
        if (j < 536) {
            int hi = j >= 268;
            int q = j - hi * 268;
            s = (q < 70) ? br[hi * 70 + q] : bw[hi * 198 + (q - 70)];
#pragma unroll
            for (int ks = 0; ks < 4; ++ks) s += part2[(size_t)ks * 69632 + j * 128 + b];
        }
        proj_s[j] = s;
    }
    // stage mem[b] -> LDS (stride 65 to kill bank conflicts)
#pragma unroll
    for (int e = 0; e < 32; ++e) {
        int flat = e * 256 + tx;
        mem_s[(flat >> 6) * 65 + (flat & 63)] = memg[b * 8192 + flat];
    }
    __syncthreads();

    for (int hi = 0; hi < 2; ++hi) {
        const int rb = hi * 268;
        // --- read addressing + read vector (uses mem BEFORE this head's write) ---
        ntm_address(proj_s + rb, mem_s, rwg + (hi * 128 + b) * 128, w_s, wg_s, red_s, tx);
        if (tx < 64) {
            float rv = 0.f;
            for (int n = 0; n < 128; ++n) rv += w_s[n] * mem_s[n * 65 + tx];
            readsg[(hi * 128 + b) * 64 + tx] = rv;
            d_out[((size_t)t * 128 + b) * 640 + 512 + hi * 64 + tx] = rv;
        }
        __syncthreads();
        // --- write addressing (same mem) ---
        ntm_address(proj_s + rb + 70, mem_s, wwsg + (hi * 128 + b) * 128, w_s, wg_s, red_s, tx);
        if (tx < 64) {
            ea_s[tx]      = sigm(proj_s[rb + 140 + tx]);   // e = sigmoid(owh[70:134])
            ea_s[64 + tx] = proj_s[rb + 204 + tx];         // a = owh[134:198]
        }
        __syncthreads();
        // --- erase/add update, write-through to global ---
#pragma unroll
        for (int e = 0; e < 32; ++e) {
            int flat = e * 256 + tx;
            int n = flat >> 6, m = flat & 63;
            float w2 = w_s[n];
            float mv = mem_s[n * 65 + m];
            mv = mv * (1.f - w2 * ea_s[m]) + w2 * ea_s[64 + m];
            mem_s[n * 65 + m] = mv;
            memg[b * 8192 + flat] = mv;
        }
        __syncthreads();
    }
}

// ---------------- host ----------------
extern "C" void kernel_launch(void* const* d_in, const int* in_sizes, int n_in,
                              void* d_out, int out_size, void* d_ws, size_t ws_size,
                              hipStream_t stream)
{
    (void)in_sizes; (void)n_in; (void)out_size; (void)ws_size;
    const float* embs     = (const float*)d_in[0];
    const int*   lens     = (const int*)  d_in[1];
    const float* mem_bias = (const float*)d_in[2];
    const float* W_ih     = (const float*)d_in[3];
    const float* W_hh     = (const float*)d_in[4];
    const float* b_ih     = (const float*)d_in[5];
    const float* b_hh     = (const float*)d_in[6];
    const float* Wr       = (const float*)d_in[7];
    const float* br       = (const float*)d_in[8];
    const float* Ww       = (const float*)d_in[9];
    const float* bw       = (const float*)d_in[10];
    const float* h0       = (const float*)d_in[11];
    const float* c0       = (const float*)d_in[12];
    const float* r0       = (const float*)d_in[13];
    float* out = (float*)d_out;
    float* ws  = (float*)d_ws;
    float* partials = ws + 1261568;   // scratch region shared (disjoint lifetimes)
    float* part2    = ws + 1261568;

    k_init<<<4928, 256, 0, stream>>>(ws, mem_bias, h0, c0, r0);
    for (int t = 0; t < 64; ++t) {
        k_gates_gemm<<<dim3(16, 4, 4), 256, 0, stream>>>(embs, W_ih, W_hh, ws, partials, t);
        k_lstm<<<256, 256, 0, stream>>>(partials, b_ih, b_hh, ws, out, lens, t);
        k_proj<<<dim3(17, 2, 4), 256, 0, stream>>>(ws, Wr, Ww, part2);
        k_memops<<<128, 256, 0, stream>>>(part2, br, bw, ws, out, t);
    }
}

// Round 2
// 3880.689 us; speedup vs baseline: 1.1911x; 1.1911x over previous
//
#include <hip/hip_runtime.h>
#include <cmath>

// IDIM=256, CDIM=512, NH=2, N=128, M=64, T=64, BSZ=128
// K = 256 + 128 + 512 = 896 ; gate rows = 2048

// ---- ws float offsets ----
// mem    [128][128][64]           @ 0          (1,048,576)
// h      [128][512]               @ 1,048,576  (65,536)
// c      [128][512]               @ 1,114,112  (65,536)
// reads  [2][128][64]             @ 1,179,648  (16,384)
// rw     [2][128][128]            @ 1,196,032  (32,768)
// wws    [2][128][128]            @ 1,228,800  (32,768)
// scratch (partials [4][128][2048] OR part2 [4][128][544]) @ 1,261,568

__device__ __forceinline__ float sigm(float x) { return 1.0f / (1.0f + expf(-x)); }
__device__ __forceinline__ float softplusf(float x) {
    return fmaxf(x, 0.0f) + log1pf(expf(-fabsf(x)));
}

// ---------------- init ----------------
__global__ void k_init(float* __restrict__ ws,
                       const float* __restrict__ mem_bias,
                       const float* __restrict__ h0,
                       const float* __restrict__ c0,
                       const float* __restrict__ r0)
{
    int i = blockIdx.x * 256 + threadIdx.x;
    if (i < 1048576) { ws[i] = mem_bias[i & 8191]; return; }
    int j = i - 1048576;
    if (j < 65536)   { ws[i] = h0[j & 511]; return; }
    j -= 65536;
    if (j < 65536)   { ws[i] = c0[j & 511]; return; }
    j -= 65536;
    if (j < 16384)   { ws[i] = r0[((j >> 13) << 6) | (j & 63)]; return; }
    j -= 16384;
    if (j < 65536)   { ws[i] = 0.0f; return; }
}

// ---------------- k1a: gates GEMM ----------------
// grid (16 row-tiles of 128, 4 b-tiles of 32, 4 K-splits of 224), 256 thr
// thread tile 4r x 4b; LDS stores k-contiguous float4 slots with XOR swizzle:
// slot' = slot ^ ((row>>2)&7)  -> ds_read_b128 conflict-free (verified mapping).
__global__ __launch_bounds__(256) void k_gates_gemm(
    const float* __restrict__ embs,   // (64,128,256)
    const float* __restrict__ W_ih,   // (2048,384)
    const float* __restrict__ W_hh,   // (2048,512)
    const float* __restrict__ ws,
    float* __restrict__ partials,
    int t)
{
    const int tx = threadIdx.x;
    const int r0 = blockIdx.x * 128;
    const int b0 = blockIdx.y * 32;
    const int kz = blockIdx.z;
    const int rg = tx >> 3;           // 0..31
    const int bg = tx & 7;            // 0..7

    __shared__ float w_s[128 * 36];
    __shared__ float x_s[32 * 36];

    float acc[4][4];
#pragma unroll
    for (int i = 0; i < 4; ++i)
#pragma unroll
        for (int j = 0; j < 4; ++j) acc[i][j] = 0.f;

    const float* hptr = ws + 1048576;
    const float* rptr = ws + 1179648;

    for (int kc = 0; kc < 7; ++kc) {
        const int kb = kz * 224 + kc * 32;
#pragma unroll
        for (int e = 0; e < 16; ++e) {
            int flat = e * 256 + tx;
            int rl = flat >> 5, kk = flat & 31;
            int r = r0 + rl, kg = kb + kk;
            float v = (kg < 384) ? W_ih[r * 384 + kg] : W_hh[r * 512 + (kg - 384)];
            int col = (kk & 3) | (((((kk >> 2) ^ (rl >> 2))) & 7) << 2);
            w_s[rl * 36 + col] = v;
        }
#pragma unroll
        for (int e = 0; e < 4; ++e) {
            int flat = e * 256 + tx;
            int bl = flat >> 5, kk = flat & 31;
            int b = b0 + bl, kg = kb + kk;
            float v;
            if      (kg < 256) v = embs[(t * 128 + b) * 256 + kg];
            else if (kg < 320) v = rptr[b * 64 + (kg - 256)];
            else if (kg < 384) v = rptr[8192 + b * 64 + (kg - 320)];
            else               v = hptr[b * 512 + (kg - 384)];
            int col = (kk & 3) | (((((kk >> 2) ^ (bl >> 2))) & 7) << 2);
            x_s[bl * 36 + col] = v;
        }
        __syncthreads();
#pragma unroll
        for (int kk4 = 0; kk4 < 8; ++kk4) {
            float4 wv[4], xv[4];
#pragma unroll
            for (int i = 0; i < 4; ++i)
                wv[i] = *reinterpret_cast<const float4*>(&w_s[(rg * 4 + i) * 36 + ((kk4 ^ (rg & 7)) << 2)]);
#pragma unroll
            for (int j = 0; j < 4; ++j)
                xv[j] = *reinterpret_cast<const float4*>(&x_s[(bg * 4 + j) * 36 + ((kk4 ^ (bg & 7)) << 2)]);
#pragma unroll
            for (int i = 0; i < 4; ++i)
#pragma unroll
                for (int j = 0; j < 4; ++j) {
                    acc[i][j] += wv[i].x * xv[j].x;
                    acc[i][j] += wv[i].y * xv[j].y;
                    acc[i][j] += wv[i].z * xv[j].z;
                    acc[i][j] += wv[i].w * xv[j].w;
                }
        }
        __syncthreads();
    }
#pragma unroll
    for (int j = 0; j < 4; ++j) {
        int b = b0 + bg * 4 + j;
        float4 v = make_float4(acc[0][j], acc[1][j], acc[2][j], acc[3][j]);
        *reinterpret_cast<float4*>(&partials[(size_t)kz * 262144 + b * 2048 + r0 + rg * 4]) = v;
    }
}

// ---------------- k1b: LSTM pointwise ----------------
__global__ __launch_bounds__(256) void k_lstm(
    const float* __restrict__ partials,
    const float* __restrict__ b_ih,
    const float* __restrict__ b_hh,
    float* __restrict__ ws,
    float* __restrict__ d_out,
    const int* __restrict__ lens,
    int t)
{
    int cell = blockIdx.x * 256 + threadIdx.x;
    int b = cell >> 9, ch = cell & 511;
    float gate[4];
#pragma unroll
    for (int g = 0; g < 4; ++g) {
        int r = g * 512 + ch;
        float s = b_ih[r] + b_hh[r];
#pragma unroll
        for (int ks = 0; ks < 4; ++ks) s += partials[(size_t)ks * 262144 + b * 2048 + r];
        gate[g] = s;
    }
    float* hp = ws + 1048576;
    float* cp = ws + 1114112;
    float c_old = cp[cell];
    float c_new = sigm(gate[1]) * c_old + sigm(gate[0]) * tanhf(gate[2]);
    float h_new = sigm(gate[3]) * tanhf(c_new);
    cp[cell] = c_new;
    hp[cell] = h_new;
    d_out[((size_t)t * 128 + b) * 640 + ch] = h_new;
    if (lens[b] - 1 == t) {
        d_out[5242880 + cell] = h_new;
        d_out[5308416 + cell] = c_new;
    }
}

// ---------------- k2: head projections ----------------
// part2 layout [ks][b][544]: coalesced consumption in k_memops.
// grid (9 j-tiles of 64, 4 b-tiles of 32, 4 K-splits of 128), 256 thr
// thread: 4j (jg=tx&15) x 2b (bg=tx>>4)
__global__ __launch_bounds__(256) void k_proj(
    const float* __restrict__ ws,
    const float* __restrict__ Wr,     // (2,70,512)
    const float* __restrict__ Ww,     // (2,198,512)
    float* __restrict__ part2)
{
    const int tx = threadIdx.x;
    const int j0 = blockIdx.x * 64;
    const int b0 = blockIdx.y * 32;
    const int kz = blockIdx.z;
    const int jg = tx & 15;
    const int bg = tx >> 4;

    __shared__ float w_s[64 * 33];
    __shared__ float h_s[32 * 33];

    const float* hptr = ws + 1048576;
    float acc[2][4] = {{0, 0, 0, 0}, {0, 0, 0, 0}};

    for (int kc = 0; kc < 4; ++kc) {
        int kb = kz * 128 + kc * 32;
#pragma unroll
        for (int e = 0; e < 8; ++e) {
            int flat = e * 256 + tx;
            int rl = flat >> 5, kk = flat & 31;
            int j = j0 + rl;
            float v = 0.f;
            if (j < 536) {
                int hi = j >= 268;
                int q = j - hi * 268;
                v = (q < 70) ? Wr[(hi * 70 + q) * 512 + kb + kk]
                             : Ww[(hi * 198 + (q - 70)) * 512 + kb + kk];
            }
            w_s[rl * 33 + kk] = v;
        }
#pragma unroll
        for (int e = 0; e < 4; ++e) {
            int flat = e * 256 + tx;
            int bl = flat >> 5, kk = flat & 31;
            h_s[bl * 33 + kk] = hptr[(b0 + bl) * 512 + kb + kk];
        }
        __syncthreads();
#pragma unroll
        for (int kk = 0; kk < 32; ++kk) {
            float hv0 = h_s[(bg * 2) * 33 + kk];
            float hv1 = h_s[(bg * 2 + 1) * 33 + kk];
            float wv[4];
#pragma unroll
            for (int i = 0; i < 4; ++i) wv[i] = w_s[(jg * 4 + i) * 33 + kk];
#pragma unroll
            for (int i = 0; i < 4; ++i) {
                acc[0][i] += hv0 * wv[i];
                acc[1][i] += hv1 * wv[i];
            }
        }
        __syncthreads();
    }
    int j = j0 + jg * 4;
    if (j < 536) {
#pragma unroll
        for (int q = 0; q < 2; ++q) {
            int b = b0 + bg * 2 + q;
            float4 v = make_float4(acc[q][0], acc[q][1], acc[q][2], acc[q][3]);
            *reinterpret_cast<float4*>(&part2[(size_t)kz * 69632 + b * 544 + j]) = v;
        }
    }
}

// ---------------- k3: per-batch memory ops ----------------
// 128 blocks x 256 thr. Waves 0-1 (grp 0) do READ addressing, waves 2-3
// (grp 1) do WRITE addressing, concurrently. Reductions: __shfl_xor within
// wave + 2-slot LDS exchange. mem_s stride 66 (2-way = free, float2 aligned).
__global__ __launch_bounds__(256) void k_memops(
    const float* __restrict__ part2,  // [4][128][544]
    const float* __restrict__ br,     // (2,70)
    const float* __restrict__ bw,     // (2,198)
    float* __restrict__ ws,
    float* __restrict__ d_out,
    int t)
{
    const int b = blockIdx.x;
    const int tx = threadIdx.x;
    const int lx = tx & 127;
    const int grp = tx >> 7;          // 0 = read head, 1 = write head
    const int wid = tx >> 6;          // wave id 0..3

    __shared__ float mem_s[128 * 66];
    __shared__ float proj_s[544];
    __shared__ float wg2_s[2 * 128];
    __shared__ float wf_s[2 * 128];   // [0]=read weights, [1]=write weights
    __shared__ float red_s[8];
    __shared__ float ea_s[128];
    __shared__ float rvp_s[4 * 66];

    float* memg   = ws;
    float* readsg = ws + 1179648;
    float* rwg    = ws + 1196032;
    float* wwsg   = ws + 1228800;

    // gather proj (coalesced along j)
    for (int j = tx; j < 544; j += 256) {
        float s = 0.f;
        if (j < 536) {
            int hi = j >= 268;
            int q = j - hi * 268;
            s = (q < 70) ? br[hi * 70 + q] : bw[hi * 198 + (q - 70)];
#pragma unroll
            for (int ks = 0; ks < 4; ++ks) s += part2[(size_t)ks * 69632 + b * 544 + j];
        }
        proj_s[j] = s;
    }
    // stage mem[b] (float4 global, float2 LDS stores)
#pragma unroll
    for (int e = 0; e < 8; ++e) {
        int f4 = e * 256 + tx;
        int n = f4 >> 4, m4 = (f4 & 15) * 4;
        float4 v = *reinterpret_cast<const float4*>(&memg[b * 8192 + f4 * 4]);
        *reinterpret_cast<float2*>(&mem_s[n * 66 + m4])     = make_float2(v.x, v.y);
        *reinterpret_cast<float2*>(&mem_s[n * 66 + m4 + 2]) = make_float2(v.z, v.w);
    }
    __syncthreads();

    for (int hi = 0; hi < 2; ++hi) {
        const float* p = proj_s + hi * 268 + grp * 70;   // {k[64],beta,g,s[3],gamma}
        float* wprev_g = (grp == 0 ? rwg : wwsg) + (hi * 128 + b) * 128;

        float beta = softplusf(p[64]);
        float g = sigm(p[65]);
        float s0 = p[66], s1 = p[67], s2 = p[68];
        float sm = fmaxf(s0, fmaxf(s1, s2));
        float e0 = expf(s0 - sm), e1 = expf(s1 - sm), e2 = expf(s2 - sm);
        float sden = e0 + e1 + e2;
        s0 = e0 / sden; s1 = e1 / sden; s2 = e2 / sden;
        float gamma = 1.0f + softplusf(p[69]);

        // cosine similarity for row n = lx
        const float* mrow = mem_s + lx * 66;
        float dot = 0.f, nm = 0.f, nk = 0.f;
#pragma unroll
        for (int m = 0; m < 64; m += 2) {
            float2 kv2 = *reinterpret_cast<const float2*>(&p[m]);
            float2 mv2 = *reinterpret_cast<const float2*>(&mrow[m]);
            float k0 = kv2.x + 1e-16f, k1 = kv2.y + 1e-16f;
            float m0 = mv2.x + 1e-16f, m1 = mv2.y + 1e-16f;
            dot += m0 * k0 + m1 * k1;
            nm  += m0 * m0 + m1 * m1;
            nk  += k0 * k0 + k1 * k1;
        }
        float sim = dot / fmaxf(sqrtf(nm) * sqrtf(nk), 1e-8f);
        float z = beta * sim;

        // softmax over the group's 128 rows: wave shfl + 2-slot exchange
        float r = z;
#pragma unroll
        for (int d = 32; d > 0; d >>= 1) r = fmaxf(r, __shfl_xor(r, d));
        if ((tx & 63) == 0) red_s[wid] = r;
        __syncthreads();
        float zmax = fmaxf(red_s[grp * 2], red_s[grp * 2 + 1]);
        float ez = expf(z - zmax);
        r = ez;
#pragma unroll
        for (int d = 32; d > 0; d >>= 1) r += __shfl_xor(r, d);
        if ((tx & 63) == 0) red_s[4 + wid] = r;
        __syncthreads();
        float zsum = red_s[4 + grp * 2] + red_s[4 + grp * 2 + 1];

        float wc = ez / zsum;
        float wgv = g * wc + (1.f - g) * wprev_g[lx];
        wg2_s[grp * 128 + lx] = wgv;
        __syncthreads();
        float wwv = s0 * wg2_s[grp * 128 + ((lx + 127) & 127)]
                  + s1 * wgv
                  + s2 * wg2_s[grp * 128 + ((lx + 1) & 127)];
        float wp = powf(wwv, gamma);
        r = wp;
#pragma unroll
        for (int d = 32; d > 0; d >>= 1) r += __shfl_xor(r, d);
        if ((tx & 63) == 0) red_s[wid] = r;
        __syncthreads();
        float psum = red_s[grp * 2] + red_s[grp * 2 + 1];
        float wfin = wp / (psum + 1e-16f);
        wf_s[grp * 128 + lx] = wfin;
        wprev_g[lx] = wfin;
        __syncthreads();

        // read vector partials (all 256 threads) + e/a prep
        {
            int m = tx & 63, p4 = tx >> 6;
            float rv = 0.f;
            const int nb = p4 * 32;
#pragma unroll
            for (int n8 = 0; n8 < 32; ++n8) {
                int n = nb + n8;
                rv += wf_s[n] * mem_s[n * 66 + m];
            }
            rvp_s[p4 * 66 + m] = rv;
        }
        if (tx < 64)        ea_s[tx] = sigm(proj_s[hi * 268 + 140 + tx]);
        else if (tx < 128)  ea_s[tx] = proj_s[hi * 268 + 204 + (tx - 64)];
        __syncthreads();

        if (tx < 64) {
            float rvf = rvp_s[tx] + rvp_s[66 + tx] + rvp_s[132 + tx] + rvp_s[198 + tx];
            readsg[(hi * 128 + b) * 64 + tx] = rvf;
            d_out[((size_t)t * 128 + b) * 640 + 512 + hi * 64 + tx] = rvf;
        }
        // erase/add update (write global only after head 1)
#pragma unroll
        for (int e = 0; e < 16; ++e) {
            int f = e * 256 + tx;              // float2 id
            int n = f >> 5, m2 = (f & 31) * 2;
            float w2 = wf_s[128 + n];
            float2 mv = *reinterpret_cast<const float2*>(&mem_s[n * 66 + m2]);
            mv.x = mv.x * (1.f - w2 * ea_s[m2])     + w2 * ea_s[64 + m2];
            mv.y = mv.y * (1.f - w2 * ea_s[m2 + 1]) + w2 * ea_s[65 + m2];
            *reinterpret_cast<float2*>(&mem_s[n * 66 + m2]) = mv;
            if (hi == 1) *reinterpret_cast<float2*>(&memg[b * 8192 + f * 2]) = mv;
        }
        __syncthreads();
    }
}

// ---------------- host ----------------
extern "C" void kernel_launch(void* const* d_in, const int* in_sizes, int n_in,
                              void* d_out, int out_size, void* d_ws, size_t ws_size,
                              hipStream_t stream)
{
    (void)in_sizes; (void)n_in; (void)out_size; (void)ws_size;
    const float* embs     = (const float*)d_in[0];
    const int*   lens     = (const int*)  d_in[1];
    const float* mem_bias = (const float*)d_in[2];
    const float* W_ih     = (const float*)d_in[3];
    const float* W_hh     = (const float*)d_in[4];
    const float* b_ih     = (const float*)d_in[5];
    const float* b_hh     = (const float*)d_in[6];
    const float* Wr       = (const float*)d_in[7];
    const float* br       = (const float*)d_in[8];
    const float* Ww       = (const float*)d_in[9];
    const float* bw       = (const float*)d_in[10];
    const float* h0       = (const float*)d_in[11];
    const float* c0       = (const float*)d_in[12];
    const float* r0       = (const float*)d_in[13];
    float* out = (float*)d_out;
    float* ws  = (float*)d_ws;
    float* partials = ws + 1261568;
    float* part2    = ws + 1261568;

    k_init<<<4928, 256, 0, stream>>>(ws, mem_bias, h0, c0, r0);
    for (int t = 0; t < 64; ++t) {
        k_gates_gemm<<<dim3(16, 4, 4), 256, 0, stream>>>(embs, W_ih, W_hh, ws, partials, t);
        k_lstm<<<256, 256, 0, stream>>>(partials, b_ih, b_hh, ws, out, lens, t);
        k_proj<<<dim3(9, 4, 4), 256, 0, stream>>>(ws, Wr, Ww, part2);
        k_memops<<<128, 256, 0, stream>>>(part2, br, bw, ws, out, t);
    }
}